// Round 4
// baseline (475.620 us; speedup 1.0000x reference)
//
#include <hip/hip_runtime.h>

// ACT module decomposition (see round 1):
//   base = inputs + time_enc; state_k = base + pos_enc[k]
//   LN stats + halting collapse to per-token scalars (fp32, bit-exact branches)
//   tstate_k = Bt + Pt_k + bt with Bt = base@Wt^T  (ONE gemm, bf16 MFMA)
//   prev = S*(Bt+bt) + sum_k w_k*Pt_k
//
// Round-4 changes:
//   - ONE prep kernel (1344 blocks): token stats (+per-block kstats by wave 0),
//     pt (blocks 1024..1279), wtconv (blocks 1280..1343). 3 fewer launches.
//   - gemm: __launch_bounds__(256,4) -> VGPR<=128 -> 4 blocks/CU -> whole
//     1024-block grid resident (no tail round). Operand-swapped MFMA gives
//     transposed D layout -> float4 stores. Epilogue PT/WW/SS/bt staged in LDS.

#define Hdim 1024
#define Ntok 16384
#define Tdim 2048
#define KHOP 12

typedef unsigned short u16;
typedef __attribute__((ext_vector_type(8))) short bf16x8;
typedef __attribute__((ext_vector_type(4))) float floatx4;
struct __align__(8) u16x4 { u16 x, y, z, w; };

static __device__ inline u16 f2bf(float f) {
    union { float f; unsigned u; } x; x.f = f;
    unsigned r = x.u + 0x7FFFu + ((x.u >> 16) & 1u);   // RNE
    return (u16)(r >> 16);
}

// ---------------- prep kernel: token stats + kstats + pt + wtconv -------------
// blocks [0,1024): token path, 16 tokens/block (4 per wave, 16 lanes/token)
// blocks [1024,1280): PT[k][o] = sum_h pos[k,h]*Wt[o,h]  (o = (b-1024)*4+wave)
// blocks [1280,1344): Wt -> bf16
__global__ __launch_bounds__(256)
void prep_kernel(const float* __restrict__ inp, const float* __restrict__ tenc,
                 const float* __restrict__ pos, const float* __restrict__ gamma,
                 const float* __restrict__ beta, const float* __restrict__ wp,
                 const float* __restrict__ bp, const float* __restrict__ Wt,
                 float* __restrict__ PT, float* __restrict__ SS,
                 float* __restrict__ WW, float* __restrict__ tail,
                 u16* __restrict__ baseBF, u16* __restrict__ WtBF) {
    __shared__ float sPos[KHOP * Hdim];   // 48 KB
    __shared__ float sGW[Hdim];           // 4 KB  gamma*wp
    __shared__ float sKst[40];
    int b = blockIdx.x, t = threadIdx.x;
    int wave = t >> 6, lane = t & 63;

    if (b >= 1024) {
        if (b < 1280) {                    // ---- pt path ----
            int o = (b - 1024) * 4 + wave;
            float acc[KHOP];
#pragma unroll
            for (int k = 0; k < KHOP; k++) acc[k] = 0.f;
            const float* wrow = Wt + (size_t)o * Hdim;
            for (int i = 0; i < 16; i++) {
                int h = lane + 64 * i;
                float w = wrow[h];
#pragma unroll
                for (int k = 0; k < KHOP; k++) acc[k] += w * pos[k * Hdim + h];
            }
#pragma unroll
            for (int k = 0; k < KHOP; k++)
                for (int off = 32; off > 0; off >>= 1) acc[k] += __shfl_xor(acc[k], off);
            if (lane == 0) {
#pragma unroll
                for (int k = 0; k < KHOP; k++) PT[k * Hdim + o] = acc[k];
            }
        } else {                           // ---- wtconv path ----
            int bb = b - 1280;
#pragma unroll
            for (int i = 0; i < 16; i++) {
                int idx = bb * 256 + t + i * 16384;
                float4 v = ((const float4*)Wt)[idx];
                u16x4 o4; o4.x = f2bf(v.x); o4.y = f2bf(v.y); o4.z = f2bf(v.z); o4.w = f2bf(v.w);
                ((u16x4*)WtBF)[idx] = o4;
            }
        }
        return;
    }

    // ---- token path ----
    for (int i = t; i < KHOP * Hdim / 4; i += 256)
        ((float4*)sPos)[i] = ((const float4*)pos)[i];
    {
        float4 gv = ((const float4*)gamma)[t];
        float4 wv = ((const float4*)wp)[t];
        ((float4*)sGW)[t] = make_float4(gv.x * wv.x, gv.y * wv.y, gv.z * wv.z, gv.w * wv.w);
    }
    __syncthreads();

    if (t < 64) {   // wave 0 computes kstats into sKst (redundant per block, cheap)
        float gw = 0.f, bw = 0.f;
        for (int i = 0; i < 16; i++) {
            int h = t + 64 * i;
            gw += sGW[h];
            bw += beta[h] * wp[h];
        }
        for (int off = 32; off > 0; off >>= 1) {
            gw += __shfl_xor(gw, off);
            bw += __shfl_xor(bw, off);
        }
        for (int k = 0; k < KHOP; k++) {
            float s = 0.f, ss = 0.f, pg = 0.f;
            for (int i = 0; i < 16; i++) {
                int h = t + 64 * i;
                float v = sPos[k * Hdim + h];
                s += v; ss += v * v; pg += v * sGW[h];
            }
            for (int off = 32; off > 0; off >>= 1) {
                s += __shfl_xor(s, off);
                ss += __shfl_xor(ss, off);
                pg += __shfl_xor(pg, off);
            }
            if (t == 0) {
                float mu = s * (1.0f / Hdim);
                sKst[k] = mu;
                sKst[12 + k] = ss - (float)Hdim * mu * mu;
                sKst[24 + k] = pg - mu * gw;
            }
        }
        if (t == 0) { sKst[36] = gw; sKst[37] = bw; sKst[38] = bp[0]; }
    }

    int grp = lane >> 4, s = lane & 15;
    int n = b * 16 + wave * 4 + grp;
    const float4* ip4 = (const float4*)(inp + (size_t)n * Hdim);
    const float4* tp4 = (const float4*)(tenc + (size_t)(n & (Tdim - 1)) * Hdim);
    u16x4* ob4 = (u16x4*)(baseBF + (size_t)n * Hdim);

    float sm = 0.f, ss = 0.f, d1 = 0.f;
    float dk[KHOP];
#pragma unroll
    for (int k = 0; k < KHOP; k++) dk[k] = 0.f;

#pragma unroll
    for (int i = 0; i < 16; i++) {
        int idx = s + 16 * i;          // float4 index within the token row
        float4 a = ip4[idx], bb = tp4[idx];
        float4 v = make_float4(a.x + bb.x, a.y + bb.y, a.z + bb.z, a.w + bb.w);
        u16x4 o4; o4.x = f2bf(v.x); o4.y = f2bf(v.y); o4.z = f2bf(v.z); o4.w = f2bf(v.w);
        ob4[idx] = o4;
        sm += v.x + v.y + v.z + v.w;
        ss += v.x * v.x + v.y * v.y + v.z * v.z + v.w * v.w;
        int h = idx * 4;
        float4 g = *(const float4*)&sGW[h];
        d1 += v.x * g.x + v.y * g.y + v.z * g.z + v.w * g.w;
#pragma unroll
        for (int k = 0; k < KHOP; k++) {
            float4 p = *(const float4*)&sPos[k * Hdim + h];
            dk[k] += v.x * p.x + v.y * p.y + v.z * p.z + v.w * p.w;
        }
    }
#pragma unroll
    for (int off = 8; off > 0; off >>= 1) {
        sm += __shfl_xor(sm, off);
        ss += __shfl_xor(ss, off);
        d1 += __shfl_xor(d1, off);
#pragma unroll
        for (int k = 0; k < KHOP; k++) dk[k] += __shfl_xor(dk[k], off);
    }

    __syncthreads();   // sKst visible (wave 0 wrote before its accumulation)

    if (s == 0) {
        float gwv = sKst[36], bwv = sKst[37], bpv = sKst[38];
        float mu = sm * (1.0f / Hdim);
        float ssb = ss - (float)Hdim * mu * mu;
        float hp = 0.f, rem = 0.f, nu = 0.f;
        float uw[KHOP];
#pragma unroll
        for (int k = 0; k < KHOP; k++) {
            float mup = sKst[k], sspk = sKst[12 + k], ek = sKst[24 + k];
            float ck = dk[k] - (float)Hdim * mu * mup;
            float var = (ssb + sspk + 2.0f * ck) * (1.0f / Hdim);
            float inv = 1.0f / sqrtf(var + 1e-5f);
            float logit = inv * (d1 - mu * gwv + ek) + bwv + bpv;
            float p = 1.0f / (1.0f + expf(-logit));
            float sr = (hp < 1.0f) ? 1.0f : 0.0f;
            float acc = hp + p * sr;
            float nh = (acc > 0.9f) ? sr : 0.0f;
            float sr2 = (acc <= 0.9f) ? sr : 0.0f;
            hp += p * sr2;
            rem += nh * (1.0f - hp);
            hp += nh * rem;
            nu += sr2 + nh;
            uw[k] = p * sr2 + nh * rem;
        }
        float prod = 1.f, S = 0.f;
        float w[KHOP];
#pragma unroll
        for (int k = KHOP - 1; k >= 0; k--) {
            w[k] = uw[k] * prod;
            prod *= (1.0f - uw[k]);
            S += w[k];
        }
        SS[n] = S;
#pragma unroll
        for (int k = 0; k < KHOP; k++) WW[k * Ntok + n] = w[k];
        tail[n] = rem;
        tail[Ntok + n] = nu;
    }
}

// ---------------- gemm: bf16 MFMA 128x128xBK64, transposed-D, fused epilogue --
// A = baseBF [M=16384, K=1024], Bt = WtBF [N=1024, K=1024] (both K-contiguous)
// out[m,o] = S[m]*(A@Bt^T + bt[o]) + sum_k WW[k][m]*PT[k][o]
// mfma(b, a, acc) -> D^T: thread holds row m = 64*wr+16*mi+l16 (fixed),
// cols n = 64*wc+16*ni+quad*4+reg (4 consecutive) -> float4 stores.
__global__ __launch_bounds__(256, 4)
void gemm_bf16(const u16* __restrict__ A, const u16* __restrict__ Bt,
               const float* __restrict__ bt, const float* __restrict__ PT,
               const float* __restrict__ SS, const float* __restrict__ WW,
               float* __restrict__ out) {
    __shared__ u16 As[128 * 64];   // 16 KB, chunks XOR-swizzled
    __shared__ u16 Bs[128 * 64];   // 16 KB
    int t = threadIdx.x;
    int bm = blockIdx.x;           // 0..127 (M tiles) — fast dim: XCD = bm%8
    int bn = blockIdx.y;           // 0..7   (N tiles)
    int gm = bm * 128, gn = bn * 128;
    int wave = t >> 6, lane = t & 63;
    int wr = wave >> 1, wc = wave & 1;     // 2x2 wave grid of 64x64 regions
    int quad = lane >> 4, l16 = lane & 15;
    int sr_ = t >> 3, sc_ = t & 7;

    floatx4 acc[4][4];
#pragma unroll
    for (int i = 0; i < 4; i++)
#pragma unroll
        for (int j = 0; j < 4; j++) acc[i][j] = (floatx4)0.f;

    for (int k0 = 0; k0 < Hdim; k0 += 64) {
#pragma unroll
        for (int i = 0; i < 4; i++) {
            int r = i * 32 + sr_;
            int cc = ((sc_ ^ (r & 7)) << 3);   // swizzled global chunk, elems
            __builtin_amdgcn_global_load_lds(
                (const __attribute__((address_space(1))) void*)(A + (size_t)(gm + r) * Hdim + k0 + cc),
                (__attribute__((address_space(3))) void*)((char*)As + i * 4096 + t * 16),
                16, 0, 0);
            __builtin_amdgcn_global_load_lds(
                (const __attribute__((address_space(1))) void*)(Bt + (size_t)(gn + r) * Hdim + k0 + cc),
                (__attribute__((address_space(3))) void*)((char*)Bs + i * 4096 + t * 16),
                16, 0, 0);
        }
        __syncthreads();
#pragma unroll
        for (int kk = 0; kk < 2; kk++) {
            int q = kk * 4 + quad;
            int pos = ((q ^ (l16 & 7)) << 3);
            bf16x8 a[4], b[4];
#pragma unroll
            for (int mi = 0; mi < 4; mi++) {
                int R = 64 * wr + 16 * mi + l16;
                a[mi] = *(const bf16x8*)&As[R * 64 + pos];
            }
#pragma unroll
            for (int ni = 0; ni < 4; ni++) {
                int R = 64 * wc + 16 * ni + l16;
                b[ni] = *(const bf16x8*)&Bs[R * 64 + pos];
            }
#pragma unroll
            for (int mi = 0; mi < 4; mi++)
#pragma unroll
                for (int ni = 0; ni < 4; ni++)
                    acc[mi][ni] = __builtin_amdgcn_mfma_f32_16x16x32_bf16(
                        b[ni], a[mi], acc[mi][ni], 0, 0, 0);   // SWAPPED -> D^T
        }
        __syncthreads();
    }

    // ---- stage epilogue tiles into LDS (reuse As/Bs space) ----
    // layout (floats): [0,1536) PTt[k][128 cols], [1536,3072) WWt[k][128 rows],
    //                  [3072,3200) SS rows, [3200,3328) bt cols
    float* eLDS = (float*)As;
    for (int j = t; j < 1536; j += 256) {
        int k = j >> 7, c = j & 127;
        eLDS[j] = PT[k * Hdim + gn + c];
        eLDS[1536 + j] = WW[k * Ntok + gm + c];
    }
    if (t < 128) {
        eLDS[3072 + t] = SS[gm + t];
        eLDS[3200 + t] = bt[gn + t];
    }
    __syncthreads();

#pragma unroll
    for (int mi = 0; mi < 4; mi++) {
        int ml = 64 * wr + 16 * mi + l16;          // local out row
        float Sv = eLDS[3072 + ml];
        float wk[KHOP];
#pragma unroll
        for (int k = 0; k < KHOP; k++) wk[k] = eLDS[1536 + k * 128 + ml];
#pragma unroll
        for (int ni = 0; ni < 4; ni++) {
            int cl = 64 * wc + 16 * ni + quad * 4; // local out col (4 consecutive)
            float4 btv = *(const float4*)&eLDS[3200 + cl];
            floatx4 v = acc[mi][ni];
            float4 r;
            r.x = Sv * (v[0] + btv.x);
            r.y = Sv * (v[1] + btv.y);
            r.z = Sv * (v[2] + btv.z);
            r.w = Sv * (v[3] + btv.w);
#pragma unroll
            for (int k = 0; k < KHOP; k++) {
                float4 p = *(const float4*)&eLDS[k * 128 + cl];
                r.x += wk[k] * p.x;
                r.y += wk[k] * p.y;
                r.z += wk[k] * p.z;
                r.w += wk[k] * p.w;
            }
            *(float4*)(out + (size_t)(gm + ml) * Hdim + gn + cl) = r;
        }
    }
}

extern "C" void kernel_launch(void* const* d_in, const int* in_sizes, int n_in,
                              void* d_out, int out_size, void* d_ws, size_t ws_size,
                              hipStream_t stream) {
    const float* inp   = (const float*)d_in[0];
    const float* tenc  = (const float*)d_in[1];
    const float* pos   = (const float*)d_in[2];
    const float* gamma = (const float*)d_in[3];
    const float* beta  = (const float*)d_in[4];
    const float* wp    = (const float*)d_in[5];
    const float* bp    = (const float*)d_in[6];
    const float* Wt    = (const float*)d_in[7];
    const float* bt    = (const float*)d_in[8];
    float* out = (float*)d_out;

    float* W = (float*)d_ws;
    float* PT  = W;                          // 12*1024
    float* SS  = PT + KHOP * Hdim;           // 16384
    float* WW  = SS + Ntok;                  // 12*16384
    u16* WtBF  = (u16*)(WW + KHOP * Ntok);   // 1M u16 = 2MB
    u16* baseBF = WtBF + (size_t)Hdim * Hdim; // 16M u16 = 32MB

    prep_kernel<<<1344, 256, 0, stream>>>(inp, tenc, pos, gamma, beta, wp, bp, Wt,
                                          PT, SS, WW, out + (size_t)Ntok * Hdim,
                                          baseBF, WtBF);
    gemm_bf16<<<dim3(128, 8), 256, 0, stream>>>(baseBF, WtBF, bt, PT, SS, WW, out);
}

// Round 5
// 304.039 us; speedup vs baseline: 1.5643x; 1.5643x over previous
//
#include <hip/hip_runtime.h>

// ACT module decomposition (see round 1):
//   base = inputs + time_enc; state_k = base + pos_enc[k]
//   LN stats + halting collapse to per-token scalars (fp32, bit-exact branches)
//   tstate_k = Bt + Pt_k + bt with Bt = base@Wt^T  (ONE gemm, bf16 MFMA)
//   prev = S*(Bt+bt) + sum_k w_k*Pt_k
//
// Round-5 changes:
//   - gemm: REVERT the (256,4) launch bound (round-4 regression: arch-VGPR
//     capped at 64 -> 830MB scratch spill). Natural VGPR ~164 (3 waves/SIMD,
//     m97-like). KEEP transposed-D epilogue (float4 stores, LDS-staged tiles).
//   - token: no LDS at all -- pos + gamma*wp read from global (L1/L2-resident
//     broadcast). Removes the 53KB occupancy cap and the staging barrier.
//   - separate small kernels again (prep merge was neutral-to-negative).

#define Hdim 1024
#define Ntok 16384
#define Tdim 2048
#define KHOP 12

typedef unsigned short u16;
typedef __attribute__((ext_vector_type(8))) short bf16x8;
typedef __attribute__((ext_vector_type(4))) float floatx4;
struct __align__(8) u16x4 { u16 x, y, z, w; };

static __device__ inline u16 f2bf(float f) {
    union { float f; unsigned u; } x; x.f = f;
    unsigned r = x.u + 0x7FFFu + ((x.u >> 16) & 1u);   // RNE
    return (u16)(r >> 16);
}

// ---------------- kernel A1: per-k pos stats + gamma*wp array ----------------
// kst layout: [0..11] mu_pk, [12..23] ssp_k, [24..35] e_k, [36] gw, [37] bw
__global__ void kstats_kernel(const float* __restrict__ pos,
                              const float* __restrict__ gamma,
                              const float* __restrict__ beta,
                              const float* __restrict__ wp,
                              float* __restrict__ kst,
                              float* __restrict__ gwArr) {
    int lane = threadIdx.x; // 64 threads
    float gw = 0.f, bw = 0.f;
    for (int i = 0; i < 16; i++) {
        int h = lane + 64 * i;
        float g = gamma[h] * wp[h];
        gwArr[h] = g;
        gw += g;
        bw += beta[h] * wp[h];
    }
    for (int off = 32; off > 0; off >>= 1) {
        gw += __shfl_xor(gw, off);
        bw += __shfl_xor(bw, off);
    }
    for (int k = 0; k < KHOP; k++) {
        float s = 0.f, ss = 0.f, pg = 0.f;
        for (int i = 0; i < 16; i++) {
            int h = lane + 64 * i;
            float v = pos[k * Hdim + h];
            s += v; ss += v * v; pg += v * gamma[h] * wp[h];
        }
        for (int off = 32; off > 0; off >>= 1) {
            s += __shfl_xor(s, off);
            ss += __shfl_xor(ss, off);
            pg += __shfl_xor(pg, off);
        }
        if (lane == 0) {
            float mu = s * (1.0f / Hdim);
            kst[k] = mu;
            kst[12 + k] = ss - (float)Hdim * mu * mu;
            kst[24 + k] = pg - mu * gw;
        }
    }
    if (lane == 0) { kst[36] = gw; kst[37] = bw; }
}

// ---------------- kernel A2: Pt[k][o] = sum_h pos[k,h]*Wt[o,h] (fp32) --------
__global__ void pt_kernel(const float* __restrict__ pos,
                          const float* __restrict__ Wt,
                          float* __restrict__ PT) {
    int wave = threadIdx.x >> 6, lane = threadIdx.x & 63;
    int o = blockIdx.x * 4 + wave;   // 256 blocks -> o in [0,1024)
    float acc[KHOP];
#pragma unroll
    for (int k = 0; k < KHOP; k++) acc[k] = 0.f;
    const float* wrow = Wt + (size_t)o * Hdim;
    for (int i = 0; i < 16; i++) {
        int h = lane + 64 * i;
        float w = wrow[h];
#pragma unroll
        for (int k = 0; k < KHOP; k++) acc[k] += w * pos[k * Hdim + h];
    }
#pragma unroll
    for (int k = 0; k < KHOP; k++)
        for (int off = 32; off > 0; off >>= 1) acc[k] += __shfl_xor(acc[k], off);
    if (lane == 0) {
#pragma unroll
        for (int k = 0; k < KHOP; k++) PT[k * Hdim + o] = acc[k];
    }
}

// ---------------- kernel A3: Wt -> bf16 ----------------
__global__ void wtconv_kernel(const float* __restrict__ Wt, u16* __restrict__ WtBF) {
    int idx = blockIdx.x * 256 + threadIdx.x;   // 262144 float4s
    float4 v = ((const float4*)Wt)[idx];
    u16x4 o; o.x = f2bf(v.x); o.y = f2bf(v.y); o.z = f2bf(v.z); o.w = f2bf(v.w);
    ((u16x4*)WtBF)[idx] = o;
}

// ---------------- kernel B: token stats + halting + base->bf16 ----------------
// 1024 blocks x 256 thr; block = 16 tokens (4 per wave, 16 lanes/token).
// NO LDS: pos + gwArr from global (L1/L2-resident; 4-way lane broadcast).
__global__ __launch_bounds__(256)
void token_kernel(const float* __restrict__ inp, const float* __restrict__ tenc,
                  const float* __restrict__ pos, const float* __restrict__ gwArr,
                  const float* __restrict__ bp, const float* __restrict__ kst,
                  float* __restrict__ SS, float* __restrict__ WW,
                  float* __restrict__ tail, u16* __restrict__ baseBF) {
    int t = threadIdx.x;
    int wave = t >> 6, lane = t & 63;
    int grp = lane >> 4, s = lane & 15;
    int n = blockIdx.x * 16 + wave * 4 + grp;

    const float4* ip4 = (const float4*)(inp + (size_t)n * Hdim);
    const float4* tp4 = (const float4*)(tenc + (size_t)(n & (Tdim - 1)) * Hdim);
    u16x4* ob4 = (u16x4*)(baseBF + (size_t)n * Hdim);
    const float4* gw4 = (const float4*)gwArr;
    const float4* pp4 = (const float4*)pos;    // [k*256 + idx]

    float sm = 0.f, ss = 0.f, d1 = 0.f;
    float dk[KHOP];
#pragma unroll
    for (int k = 0; k < KHOP; k++) dk[k] = 0.f;

#pragma unroll
    for (int i = 0; i < 16; i++) {
        int idx = s + 16 * i;          // float4 index within the token row
        float4 a = ip4[idx], b = tp4[idx];
        float4 v = make_float4(a.x + b.x, a.y + b.y, a.z + b.z, a.w + b.w);
        u16x4 o4; o4.x = f2bf(v.x); o4.y = f2bf(v.y); o4.z = f2bf(v.z); o4.w = f2bf(v.w);
        ob4[idx] = o4;
        sm += v.x + v.y + v.z + v.w;
        ss += v.x * v.x + v.y * v.y + v.z * v.z + v.w * v.w;
        float4 g = gw4[idx];
        d1 += v.x * g.x + v.y * g.y + v.z * g.z + v.w * g.w;
#pragma unroll
        for (int k = 0; k < KHOP; k++) {
            float4 p = pp4[k * 256 + idx];
            dk[k] += v.x * p.x + v.y * p.y + v.z * p.z + v.w * p.w;
        }
    }
    // reduce across the 16 lanes of this token's group
#pragma unroll
    for (int off = 8; off > 0; off >>= 1) {
        sm += __shfl_xor(sm, off);
        ss += __shfl_xor(ss, off);
        d1 += __shfl_xor(d1, off);
#pragma unroll
        for (int k = 0; k < KHOP; k++) dk[k] += __shfl_xor(dk[k], off);
    }

    if (s == 0) {
        float gwv = kst[36], bwv = kst[37], bpv = bp[0];
        float mu = sm * (1.0f / Hdim);
        float ssb = ss - (float)Hdim * mu * mu;
        float hp = 0.f, rem = 0.f, nu = 0.f;
        float uw[KHOP];
#pragma unroll
        for (int k = 0; k < KHOP; k++) {
            float mup = kst[k], sspk = kst[12 + k], ek = kst[24 + k];
            float ck = dk[k] - (float)Hdim * mu * mup;
            float var = (ssb + sspk + 2.0f * ck) * (1.0f / Hdim);
            float inv = 1.0f / sqrtf(var + 1e-5f);
            float logit = inv * (d1 - mu * gwv + ek) + bwv + bpv;
            float p = 1.0f / (1.0f + expf(-logit));
            float sr = (hp < 1.0f) ? 1.0f : 0.0f;
            float acc = hp + p * sr;
            float nh = (acc > 0.9f) ? sr : 0.0f;
            float sr2 = (acc <= 0.9f) ? sr : 0.0f;
            hp += p * sr2;
            rem += nh * (1.0f - hp);
            hp += nh * rem;
            nu += sr2 + nh;
            uw[k] = p * sr2 + nh * rem;
        }
        float prod = 1.f, S = 0.f;
        float w[KHOP];
#pragma unroll
        for (int k = KHOP - 1; k >= 0; k--) {
            w[k] = uw[k] * prod;
            prod *= (1.0f - uw[k]);
            S += w[k];
        }
        SS[n] = S;
#pragma unroll
        for (int k = 0; k < KHOP; k++) WW[k * Ntok + n] = w[k];
        tail[n] = rem;
        tail[Ntok + n] = nu;
    }
}

// ---------------- gemm: bf16 MFMA 128x128xBK64, transposed-D, fused epilogue --
// A = baseBF [M=16384, K=1024], Bt = WtBF [N=1024, K=1024] (both K-contiguous)
// out[m,o] = S[m]*(A@Bt^T + bt[o]) + sum_k WW[k][m]*PT[k][o]
// mfma(b, a, acc) -> D^T: thread holds row m = 64*wr+16*mi+l16 (fixed),
// cols n = 64*wc+16*ni+quad*4+reg (4 consecutive) -> float4 stores.
// NOTE: no min-waves bound! (256,4) caps arch-VGPR at 64 -> 830MB spill (r4).
__global__ __launch_bounds__(256)
void gemm_bf16(const u16* __restrict__ A, const u16* __restrict__ Bt,
               const float* __restrict__ bt, const float* __restrict__ PT,
               const float* __restrict__ SS, const float* __restrict__ WW,
               float* __restrict__ out) {
    __shared__ u16 As[128 * 64];   // 16 KB, chunks XOR-swizzled
    __shared__ u16 Bs[128 * 64];   // 16 KB
    int t = threadIdx.x;
    int bm = blockIdx.x;           // 0..127 (M tiles) — fast dim: XCD = bm%8
    int bn = blockIdx.y;           // 0..7   (N tiles)
    int gm = bm * 128, gn = bn * 128;
    int wave = t >> 6, lane = t & 63;
    int wr = wave >> 1, wc = wave & 1;     // 2x2 wave grid of 64x64 regions
    int quad = lane >> 4, l16 = lane & 15;
    int sr_ = t >> 3, sc_ = t & 7;

    floatx4 acc[4][4];
#pragma unroll
    for (int i = 0; i < 4; i++)
#pragma unroll
        for (int j = 0; j < 4; j++) acc[i][j] = (floatx4)0.f;

    for (int k0 = 0; k0 < Hdim; k0 += 64) {
#pragma unroll
        for (int i = 0; i < 4; i++) {
            int r = i * 32 + sr_;
            int cc = ((sc_ ^ (r & 7)) << 3);   // swizzled global chunk, elems
            __builtin_amdgcn_global_load_lds(
                (const __attribute__((address_space(1))) void*)(A + (size_t)(gm + r) * Hdim + k0 + cc),
                (__attribute__((address_space(3))) void*)((char*)As + i * 4096 + t * 16),
                16, 0, 0);
            __builtin_amdgcn_global_load_lds(
                (const __attribute__((address_space(1))) void*)(Bt + (size_t)(gn + r) * Hdim + k0 + cc),
                (__attribute__((address_space(3))) void*)((char*)Bs + i * 4096 + t * 16),
                16, 0, 0);
        }
        __syncthreads();
#pragma unroll
        for (int kk = 0; kk < 2; kk++) {
            int q = kk * 4 + quad;
            int pos_ = ((q ^ (l16 & 7)) << 3);
            bf16x8 a[4], b[4];
#pragma unroll
            for (int mi = 0; mi < 4; mi++) {
                int R = 64 * wr + 16 * mi + l16;
                a[mi] = *(const bf16x8*)&As[R * 64 + pos_];
            }
#pragma unroll
            for (int ni = 0; ni < 4; ni++) {
                int R = 64 * wc + 16 * ni + l16;
                b[ni] = *(const bf16x8*)&Bs[R * 64 + pos_];
            }
#pragma unroll
            for (int mi = 0; mi < 4; mi++)
#pragma unroll
                for (int ni = 0; ni < 4; ni++)
                    acc[mi][ni] = __builtin_amdgcn_mfma_f32_16x16x32_bf16(
                        b[ni], a[mi], acc[mi][ni], 0, 0, 0);   // SWAPPED -> D^T
        }
        __syncthreads();
    }

    // ---- stage epilogue tiles into LDS (reuse As/Bs space) ----
    // layout (floats): [0,1536) PTt[k][128 cols], [1536,3072) WWt[k][128 rows],
    //                  [3072,3200) SS rows, [3200,3328) bt cols
    float* eLDS = (float*)As;
    for (int j = t; j < 1536; j += 256) {
        int k = j >> 7, c = j & 127;
        eLDS[j] = PT[k * Hdim + gn + c];
        eLDS[1536 + j] = WW[k * Ntok + gm + c];
    }
    if (t < 128) {
        eLDS[3072 + t] = SS[gm + t];
        eLDS[3200 + t] = bt[gn + t];
    }
    __syncthreads();

#pragma unroll
    for (int mi = 0; mi < 4; mi++) {
        int ml = 64 * wr + 16 * mi + l16;          // local out row
        float Sv = eLDS[3072 + ml];
        float wk[KHOP];
#pragma unroll
        for (int k = 0; k < KHOP; k++) wk[k] = eLDS[1536 + k * 128 + ml];
#pragma unroll
        for (int ni = 0; ni < 4; ni++) {
            int cl = 64 * wc + 16 * ni + quad * 4; // local out col (4 consecutive)
            float4 btv = *(const float4*)&eLDS[3200 + cl];
            floatx4 v = acc[mi][ni];
            float4 r;
            r.x = Sv * (v[0] + btv.x);
            r.y = Sv * (v[1] + btv.y);
            r.z = Sv * (v[2] + btv.z);
            r.w = Sv * (v[3] + btv.w);
#pragma unroll
            for (int k = 0; k < KHOP; k++) {
                float4 p = *(const float4*)&eLDS[k * 128 + cl];
                r.x += wk[k] * p.x;
                r.y += wk[k] * p.y;
                r.z += wk[k] * p.z;
                r.w += wk[k] * p.w;
            }
            *(float4*)(out + (size_t)(gm + ml) * Hdim + gn + cl) = r;
        }
    }
}

extern "C" void kernel_launch(void* const* d_in, const int* in_sizes, int n_in,
                              void* d_out, int out_size, void* d_ws, size_t ws_size,
                              hipStream_t stream) {
    const float* inp   = (const float*)d_in[0];
    const float* tenc  = (const float*)d_in[1];
    const float* pos   = (const float*)d_in[2];
    const float* gamma = (const float*)d_in[3];
    const float* beta  = (const float*)d_in[4];
    const float* wp    = (const float*)d_in[5];
    const float* bp    = (const float*)d_in[6];
    const float* Wt    = (const float*)d_in[7];
    const float* bt    = (const float*)d_in[8];
    float* out = (float*)d_out;

    float* W = (float*)d_ws;
    float* kst = W;                          // 64 floats
    float* gwArr = W + 64;                   // 1024 floats
    float* PT  = gwArr + Hdim;               // 12*1024
    float* SS  = PT + KHOP * Hdim;           // 16384
    float* WW  = SS + Ntok;                  // 12*16384
    u16* WtBF  = (u16*)(WW + KHOP * Ntok);   // 1M u16 = 2MB
    u16* baseBF = WtBF + (size_t)Hdim * Hdim; // 16M u16 = 32MB

    kstats_kernel<<<1, 64, 0, stream>>>(pos, gamma, beta, wp, kst, gwArr);
    wtconv_kernel<<<1024, 256, 0, stream>>>(Wt, WtBF);
    pt_kernel<<<256, 256, 0, stream>>>(pos, Wt, PT);
    token_kernel<<<1024, 256, 0, stream>>>(inp, tenc, pos, gwArr, bp, kst,
                                           SS, WW, out + (size_t)Ntok * Hdim, baseBF);
    gemm_bf16<<<dim3(128, 8), 256, 0, stream>>>(baseBF, WtBF, bt, PT, SS, WW, out);
}